// Round 9
// baseline (24.521 us; speedup 1.0000x reference)
//
#include <hip/hip_runtime.h>

// BilateralSliceApply: grid [4,12,8,16,16] f32, guide [4,1024,1024] f32,
// image [4,3,1024,1024] f32 -> out [4,3,1024,1024] f32.
//
// One block per image row; y-lerped grid slab in LDS as fp16 Z-PAIRS
// (dword s[x*100 + z*12 + c] = half2(a[c,z], a[c,min(z+1,7)])); bilinear
// (x,z) interp via v_dot2_f32_f16 (2 fdot2/channel, f32 accum).
// THIS ROUND: minimize instruction issue. float4 I/O everywhere (7 VMEM
// instr/thread instead of 40); each thread owns 4 CONSECUTIVE pixels
// (aligned group never straddles an x-cell: boundaries at 64k+31.5), so
// x-math is hoisted once per thread; tx_j = tx0 + j/64.

typedef _Float16 h2 __attribute__((ext_vector_type(2)));

static __device__ __forceinline__ float fdot2f(h2 a, h2 b, float c) {
#if __has_builtin(__builtin_amdgcn_fdot2)
    return __builtin_amdgcn_fdot2(a, b, c, false);
#else
    return (float)a.x * (float)b.x + (float)a.y * (float)b.y + c;
#endif
}

static __device__ __forceinline__ h2 bch2(unsigned u) {
    return __builtin_bit_cast(h2, u);
}

static constexpr int C_ = 12, D_ = 8, GH_ = 16, GW_ = 16;
static constexpr int H_ = 1024, W_ = 1024;
static constexpr int HW_ = H_ * W_;
static constexpr int XS = D_ * C_ + 4;   // 100 dword slots per x-slab

__global__ __launch_bounds__(256) void bsa_v4_kernel(
    const float* __restrict__ grid,   // [B][C][D][GH][GW]
    const float* __restrict__ guide,  // [B][H][W]
    const float* __restrict__ image,  // [B][3][H][W]
    float* __restrict__ out)          // [B][3][H][W]
{
    __shared__ unsigned s[GW_ * XS];  // 6.4 KB; dword = half2 z-pair

    const int bid = blockIdx.x;       // = b*H + y
    const int y = bid & (H_ - 1);
    const int b = bid >> 10;
    const int t = threadIdx.x;

    // ---- y interpolation factors (uniform across block) ----
    const float gyc = (y + 0.5f) * (1.0f / 64.0f) - 0.5f;
    const float fy = floorf(gyc);
    const float ty = gyc - fy;
    const int iy = (int)fy;
    const int y0 = min(max(iy, 0), GH_ - 1);
    const int y1 = min(max(iy + 1, 0), GH_ - 1);

    // ---- slab global loads first (threads 0..191): x=t&15, c=t>>4, z=0..7 ----
    const int sx = t & 15, sc = t >> 4;
    float sv0[8], sv1[8];
    const float* gb = grid + b * (C_ * D_ * GH_ * GW_);
    if (t < 192) {
        const int base = sc * (D_ * GH_ * GW_) + sx;
#pragma unroll
        for (int z = 0; z < 8; ++z) {
            sv0[z] = gb[base + z * (GH_ * GW_) + y0 * GW_];
            sv1[z] = gb[base + z * (GH_ * GW_) + y1 * GW_];
        }
    }

    // ---- pixel loads: float4, 4 consecutive px per thread ----
    const int xp = t << 2;
    const float* gdp = guide + (size_t)bid * W_;
    const float* imp = image + (size_t)b * 3 * HW_ + (size_t)y * W_;
    const float4 gd = *(const float4*)(gdp + xp);
    const float4 ir = *(const float4*)(imp + xp);
    const float4 ig = *(const float4*)(imp + HW_ + xp);
    const float4 ibv = *(const float4*)(imp + 2 * (size_t)HW_ + xp);

    // ---- y-lerp, build fp16 z-pairs, write slab ----
    if (t < 192) {
        float a[8];
#pragma unroll
        for (int z = 0; z < 8; ++z)
            a[z] = sv0[z] + ty * (sv1[z] - sv0[z]);
        const int sl = sx * XS + sc;
#pragma unroll
        for (int z = 0; z < 8; ++z) {
            const int zn = (z < 7) ? z + 1 : 7;
            h2 v = {(_Float16)a[z], (_Float16)a[zn]};
            s[sl + z * C_] = __builtin_bit_cast(unsigned, v);
        }
    }
    __syncthreads();

    // ---- x-cell: uniform across the thread's aligned 4-px group ----
    const float gxc0 = (xp + 0.5f) * (1.0f / 64.0f) - 0.5f;
    const float fx = floorf(gxc0);
    const int ix = (int)fx;
    const int x0 = min(max(ix, 0), GW_ - 1);
    const int x1 = min(max(ix + 1, 0), GW_ - 1);
    const float tx0 = gxc0 - fx;
    const unsigned* sb0 = s + x0 * XS;
    const unsigned* sb1 = s + x1 * XS;

    const float gzv[4] = {gd.x, gd.y, gd.z, gd.w};
    const float rv[4]  = {ir.x, ir.y, ir.z, ir.w};
    const float gv[4]  = {ig.x, ig.y, ig.z, ig.w};
    const float bv[4]  = {ibv.x, ibv.y, ibv.z, ibv.w};
    float o0[4], o1[4], o2[4];

#pragma unroll
    for (int j = 0; j < 4; ++j) {
        const float gz = gzv[j] * (float)D_ - 0.5f;
        const float fz = floorf(gz);
        const int iz = (int)fz;                         // in [-1, 7]
        const float tz = (iz < 0) ? 0.0f : (gz - fz);   // iz==-1 -> exact a[0]
        const int z0 = max(iz, 0);                      // iz==7 -> (a7,a7) pair

        const float tx = tx0 + j * (1.0f / 64.0f);
        const float omtx = 1.0f - tx, omtz = 1.0f - tz;
        const h2 wA = {(_Float16)(omtz * omtx), (_Float16)(tz * omtx)};
        const h2 wB = {(_Float16)(omtz * tx),   (_Float16)(tz * tx)};

        const uint4* q0 = (const uint4*)(sb0 + z0 * C_);   // 16B-aligned
        const uint4* q1 = (const uint4*)(sb1 + z0 * C_);
        const uint4 A0 = q0[0], A1 = q0[1], A2 = q0[2];
        const uint4 B0 = q1[0], B1 = q1[1], B2 = q1[2];

        float a0  = fdot2f(bch2(B0.x), wB, fdot2f(bch2(A0.x), wA, 0.0f));
        float a1  = fdot2f(bch2(B0.y), wB, fdot2f(bch2(A0.y), wA, 0.0f));
        float a2  = fdot2f(bch2(B0.z), wB, fdot2f(bch2(A0.z), wA, 0.0f));
        float a3  = fdot2f(bch2(B0.w), wB, fdot2f(bch2(A0.w), wA, 0.0f));
        float a4  = fdot2f(bch2(B1.x), wB, fdot2f(bch2(A1.x), wA, 0.0f));
        float a5  = fdot2f(bch2(B1.y), wB, fdot2f(bch2(A1.y), wA, 0.0f));
        float a6  = fdot2f(bch2(B1.z), wB, fdot2f(bch2(A1.z), wA, 0.0f));
        float a7  = fdot2f(bch2(B1.w), wB, fdot2f(bch2(A1.w), wA, 0.0f));
        float a8  = fdot2f(bch2(B2.x), wB, fdot2f(bch2(A2.x), wA, 0.0f));
        float a9  = fdot2f(bch2(B2.y), wB, fdot2f(bch2(A2.y), wA, 0.0f));
        float a10 = fdot2f(bch2(B2.z), wB, fdot2f(bch2(A2.z), wA, 0.0f));
        float a11 = fdot2f(bch2(B2.w), wB, fdot2f(bch2(A2.w), wA, 0.0f));

        o0[j] = fmaf(a0, rv[j], fmaf(a1, gv[j], fmaf(a2,  bv[j], a3)));
        o1[j] = fmaf(a4, rv[j], fmaf(a5, gv[j], fmaf(a6,  bv[j], a7)));
        o2[j] = fmaf(a8, rv[j], fmaf(a9, gv[j], fmaf(a10, bv[j], a11)));
    }

    // ---- float4 stores ----
    float* const ob = out + (size_t)b * 3 * HW_ + (size_t)y * W_ + xp;
    *(float4*)(ob)                   = make_float4(o0[0], o0[1], o0[2], o0[3]);
    *(float4*)(ob + HW_)             = make_float4(o1[0], o1[1], o1[2], o1[3]);
    *(float4*)(ob + 2 * (size_t)HW_) = make_float4(o2[0], o2[1], o2[2], o2[3]);
}

extern "C" void kernel_launch(void* const* d_in, const int* in_sizes, int n_in,
                              void* d_out, int out_size, void* d_ws, size_t ws_size,
                              hipStream_t stream) {
    const float* grid  = (const float*)d_in[0];
    const float* guide = (const float*)d_in[1];
    const float* image = (const float*)d_in[2];
    float* out = (float*)d_out;
    (void)d_ws; (void)ws_size;

    bsa_v4_kernel<<<4 * H_, 256, 0, stream>>>(grid, guide, image, out);
}

// Round 10
// 24.145 us; speedup vs baseline: 1.0156x; 1.0156x over previous
//
#include <hip/hip_runtime.h>

// BilateralSliceApply: grid [4,12,8,16,16] f32, guide [4,1024,1024] f32,
// image [4,3,1024,1024] f32 -> out [4,3,1024,1024] f32.
//
// 1024 blocks x 256 threads; each block owns 4 consecutive rows, which
// always share a y-band (band edges at y=32+64n). Raw grid pair lives in
// REGISTERS for the whole block; per-row slab is re-lerped from regs into
// LDS (fp16 z-pairs, dword = half2(a[z], a[min(z+1,7)])). Row r+1's pixel
// loads are issued before computing row r -> continuous HBM streaming
// instead of per-block load bursts. Interp via v_dot2_f32_f16.

typedef _Float16 h2 __attribute__((ext_vector_type(2)));

static __device__ __forceinline__ float fdot2f(h2 a, h2 b, float c) {
#if __has_builtin(__builtin_amdgcn_fdot2)
    return __builtin_amdgcn_fdot2(a, b, c, false);
#else
    return (float)a.x * (float)b.x + (float)a.y * (float)b.y + c;
#endif
}

static __device__ __forceinline__ h2 bch2(unsigned u) {
    return __builtin_bit_cast(h2, u);
}

static constexpr int C_ = 12, D_ = 8, GH_ = 16, GW_ = 16;
static constexpr int H_ = 1024, W_ = 1024;
static constexpr int HW_ = H_ * W_;
static constexpr int XS = D_ * C_ + 4;   // 100 dword slots per x-slab
static constexpr int R_ = 4;             // rows per block (4 | band size)

__global__ __launch_bounds__(256) void bsa_pipe4_kernel(
    const float* __restrict__ grid,   // [B][C][D][GH][GW]
    const float* __restrict__ guide,  // [B][H][W]
    const float* __restrict__ image,  // [B][3][H][W]
    float* __restrict__ out)          // [B][3][H][W]
{
    __shared__ unsigned s[GW_ * XS];  // 6.4 KB; dword = half2 z-pair

    const int row0 = blockIdx.x * R_;     // = b*H + y00
    const int y00 = row0 & (H_ - 1);
    const int b = row0 >> 10;             // H % R_ == 0: no batch crossing
    const int t = threadIdx.x;
    const int xp = t << 2;

    // ---- y-band factors, shared by all R_ rows (same fy across chunk) ----
    const float gyc = (y00 + 0.5f) * (1.0f / 64.0f) - 0.5f;
    const float fy = floorf(gyc);
    const float ty0 = gyc - fy;
    const int iy = (int)fy;
    const int yA = min(max(iy, 0), GH_ - 1);
    const int yB = min(max(iy + 1, 0), GH_ - 1);

    // ---- raw grid pair -> registers, ONCE per block (t<192) ----
    const int sx = t & 15, sc = t >> 4;
    float sv0[8], sv1[8];
    const float* gb = grid + b * (C_ * D_ * GH_ * GW_);
    if (t < 192) {
        const int base = sc * (D_ * GH_ * GW_) + sx;
#pragma unroll
        for (int z = 0; z < 8; ++z) {
            sv0[z] = gb[base + z * (GH_ * GW_) + yA * GW_];
            sv1[z] = gb[base + z * (GH_ * GW_) + yB * GW_];
        }
    }

    // ---- row-0 pixel loads (in flight under grid-load wait) ----
    const float* gdp = guide + (size_t)b * HW_;
    const float* imp = image + (size_t)b * 3 * HW_;
    float* const op  = out   + (size_t)b * 3 * HW_;

    const size_t r0 = (size_t)y00 * W_ + xp;
    float4 cur_gd = *(const float4*)(gdp + r0);
    float4 cur_ir = *(const float4*)(imp + r0);
    float4 cur_ig = *(const float4*)(imp + HW_ + r0);
    float4 cur_ib = *(const float4*)(imp + 2 * (size_t)HW_ + r0);

    // ---- slab(row 0): lerp from regs, pack z-pairs ----
    if (t < 192) {
        float a[8];
#pragma unroll
        for (int z = 0; z < 8; ++z)
            a[z] = sv0[z] + ty0 * (sv1[z] - sv0[z]);
        const int sl = sx * XS + sc;
#pragma unroll
        for (int z = 0; z < 8; ++z) {
            const int zn = (z < 7) ? z + 1 : 7;
            h2 v = {(_Float16)a[z], (_Float16)a[zn]};
            s[sl + z * C_] = __builtin_bit_cast(unsigned, v);
        }
    }
    __syncthreads();

    // ---- per-thread x-cell (constant across rows; aligned 4-px groups
    // never straddle x-cell boundaries at 64k+31.5) ----
    const float gxc0 = (xp + 0.5f) * (1.0f / 64.0f) - 0.5f;
    const float fx = floorf(gxc0);
    const int ix = (int)fx;
    const int x0 = min(max(ix, 0), GW_ - 1);
    const int x1 = min(max(ix + 1, 0), GW_ - 1);
    const float tx0 = gxc0 - fx;
    const unsigned* sb0 = s + x0 * XS;
    const unsigned* sb1 = s + x1 * XS;

#pragma unroll
    for (int r = 0; r < R_; ++r) {
        const int y = y00 + r;

        // ---- prefetch row r+1 pixels (hidden under row-r compute) ----
        float4 nxt_gd, nxt_ir, nxt_ig, nxt_ib;
        if (r + 1 < R_) {
            const size_t rn = (size_t)(y + 1) * W_ + xp;
            nxt_gd = *(const float4*)(gdp + rn);
            nxt_ir = *(const float4*)(imp + rn);
            nxt_ig = *(const float4*)(imp + HW_ + rn);
            nxt_ib = *(const float4*)(imp + 2 * (size_t)HW_ + rn);
        }

        // ---- compute row y from cur regs + slab ----
        const float gzv[4] = {cur_gd.x, cur_gd.y, cur_gd.z, cur_gd.w};
        const float rv[4]  = {cur_ir.x, cur_ir.y, cur_ir.z, cur_ir.w};
        const float gv[4]  = {cur_ig.x, cur_ig.y, cur_ig.z, cur_ig.w};
        const float bv[4]  = {cur_ib.x, cur_ib.y, cur_ib.z, cur_ib.w};
        float o0[4], o1[4], o2[4];

#pragma unroll
        for (int j = 0; j < 4; ++j) {
            const float gz = gzv[j] * (float)D_ - 0.5f;
            const float fz = floorf(gz);
            const int iz = (int)fz;                        // in [-1, 7]
            const float tz = (iz < 0) ? 0.0f : (gz - fz);  // iz==-1 -> exact a[0]
            const int z0 = max(iz, 0);                     // iz==7 -> (a7,a7)

            const float tx = tx0 + j * (1.0f / 64.0f);
            const float omtx = 1.0f - tx, omtz = 1.0f - tz;
            const h2 wA = {(_Float16)(omtz * omtx), (_Float16)(tz * omtx)};
            const h2 wB = {(_Float16)(omtz * tx),   (_Float16)(tz * tx)};

            const uint4* q0 = (const uint4*)(sb0 + z0 * C_);   // 16B-aligned
            const uint4* q1 = (const uint4*)(sb1 + z0 * C_);
            const uint4 A0 = q0[0], A1 = q0[1], A2 = q0[2];
            const uint4 B0 = q1[0], B1 = q1[1], B2 = q1[2];

            float a0  = fdot2f(bch2(B0.x), wB, fdot2f(bch2(A0.x), wA, 0.0f));
            float a1  = fdot2f(bch2(B0.y), wB, fdot2f(bch2(A0.y), wA, 0.0f));
            float a2  = fdot2f(bch2(B0.z), wB, fdot2f(bch2(A0.z), wA, 0.0f));
            float a3  = fdot2f(bch2(B0.w), wB, fdot2f(bch2(A0.w), wA, 0.0f));
            float a4  = fdot2f(bch2(B1.x), wB, fdot2f(bch2(A1.x), wA, 0.0f));
            float a5  = fdot2f(bch2(B1.y), wB, fdot2f(bch2(A1.y), wA, 0.0f));
            float a6  = fdot2f(bch2(B1.z), wB, fdot2f(bch2(A1.z), wA, 0.0f));
            float a7  = fdot2f(bch2(B1.w), wB, fdot2f(bch2(A1.w), wA, 0.0f));
            float a8  = fdot2f(bch2(B2.x), wB, fdot2f(bch2(A2.x), wA, 0.0f));
            float a9  = fdot2f(bch2(B2.y), wB, fdot2f(bch2(A2.y), wA, 0.0f));
            float a10 = fdot2f(bch2(B2.z), wB, fdot2f(bch2(A2.z), wA, 0.0f));
            float a11 = fdot2f(bch2(B2.w), wB, fdot2f(bch2(A2.w), wA, 0.0f));

            o0[j] = fmaf(a0, rv[j], fmaf(a1, gv[j], fmaf(a2,  bv[j], a3)));
            o1[j] = fmaf(a4, rv[j], fmaf(a5, gv[j], fmaf(a6,  bv[j], a7)));
            o2[j] = fmaf(a8, rv[j], fmaf(a9, gv[j], fmaf(a10, bv[j], a11)));
        }

        float* const ob = op + (size_t)y * W_ + xp;
        *(float4*)(ob)                   = make_float4(o0[0], o0[1], o0[2], o0[3]);
        *(float4*)(ob + HW_)             = make_float4(o1[0], o1[1], o1[2], o1[3]);
        *(float4*)(ob + 2 * (size_t)HW_) = make_float4(o2[0], o2[1], o2[2], o2[3]);

        __syncthreads();                  // all slab reads for row y done
        if (r + 1 < R_) {
            if (t < 192) {                // re-lerp slab from REGISTERS
                const float tyr = ty0 + (r + 1) * (1.0f / 64.0f);
                float a[8];
#pragma unroll
                for (int z = 0; z < 8; ++z)
                    a[z] = sv0[z] + tyr * (sv1[z] - sv0[z]);
                const int sl = sx * XS + sc;
#pragma unroll
                for (int z = 0; z < 8; ++z) {
                    const int zn = (z < 7) ? z + 1 : 7;
                    h2 v = {(_Float16)a[z], (_Float16)a[zn]};
                    s[sl + z * C_] = __builtin_bit_cast(unsigned, v);
                }
            }
            __syncthreads();              // slab(row y+1) ready
            cur_gd = nxt_gd; cur_ir = nxt_ir;
            cur_ig = nxt_ig; cur_ib = nxt_ib;
        }
    }
}

extern "C" void kernel_launch(void* const* d_in, const int* in_sizes, int n_in,
                              void* d_out, int out_size, void* d_ws, size_t ws_size,
                              hipStream_t stream) {
    const float* grid  = (const float*)d_in[0];
    const float* guide = (const float*)d_in[1];
    const float* image = (const float*)d_in[2];
    float* out = (float*)d_out;
    (void)d_ws; (void)ws_size;

    bsa_pipe4_kernel<<<(4 * H_) / R_, 256, 0, stream>>>(grid, guide, image, out);
}